// Round 13
// baseline (566.888 us; speedup 1.0000x reference)
//
#include <hip/hip_runtime.h>

#define B_ 16
#define T_ 128
#define OBS_ 64
#define SLOTS_ 67
#define E_ 32
#define H_ 4
#define HD_ 8
#define FFN_ 64

typedef _Float16 h2 __attribute__((ext_vector_type(2)));
typedef _Float16 h8 __attribute__((ext_vector_type(8)));
typedef __fp16 mh8 __attribute__((ext_vector_type(8)));
typedef float fx4 __attribute__((ext_vector_type(4)));
union H8 { h8 v; h2 h[4]; };

// fp16 weight block layout (halves): Wq 0 | Wk 1024 | Wv 2048 | Wo 3072 |
// Wg 4096 | Wvl 6144 | Wout 8192  (10240 halves per transformer block)
#define WBLK 10240
#define X16_BYTES (B_ * T_ * SLOTS_ * E_ * 2)  // 8,781,824 (X stored fp16)

__device__ __forceinline__ float red32(float v) {
  v += __shfl_xor(v, 16); v += __shfl_xor(v, 8); v += __shfl_xor(v, 4);
  v += __shfl_xor(v, 2);  v += __shfl_xor(v, 1);
  return v;
}
__device__ __forceinline__ float red8(float v) {
  v += __shfl_xor(v, 4); v += __shfl_xor(v, 2); v += __shfl_xor(v, 1);
  return v;
}
__device__ __forceinline__ h2 pkrtz(float x, float y) {
  return __builtin_bit_cast(h2, __builtin_amdgcn_cvt_pkrtz(x, y));
}
__device__ __forceinline__ fx4 mfma16(h8 a, h8 b, fx4 c) {
  return __builtin_amdgcn_mfma_f32_16x16x32_f16(
      __builtin_bit_cast(mh8, a), __builtin_bit_cast(mh8, b), c, 0, 0, 0);
}

// ---------------- weight pre-conversion to fp16 ----------------
struct WPtrs {
  const float *sWq, *sWk, *sWv, *sWo, *sWg, *sWvl, *sWout;
  const float *tWq, *tWk, *tWv, *tWo, *tWg, *tWvl, *tWout;
};

__global__ __launch_bounds__(256) void cvt_weights_kernel(WPtrs p, _Float16* dst) {
  int i = blockIdx.x * 256 + threadIdx.x;  // pair index
  const int total_pairs = 5 * WBLK / 2;    // 25600
  if (i >= total_pairs) return;
  int blk = i / (WBLK / 2);
  int f = (i % (WBLK / 2)) * 2;
  bool sp = blk < 3;
  int bi = sp ? blk : blk - 3;
  const float* src;
  int o;
  if (f < 1024)      { src = (sp ? p.sWq : p.tWq) + bi * 1024;  o = f; }
  else if (f < 2048) { src = (sp ? p.sWk : p.tWk) + bi * 1024;  o = f - 1024; }
  else if (f < 3072) { src = (sp ? p.sWv : p.tWv) + bi * 1024;  o = f - 2048; }
  else if (f < 4096) { src = (sp ? p.sWo : p.tWo) + bi * 1024;  o = f - 3072; }
  else if (f < 6144) { src = (sp ? p.sWg : p.tWg) + bi * 2048;  o = f - 4096; }
  else if (f < 8192) { src = (sp ? p.sWvl : p.tWvl) + bi * 2048; o = f - 6144; }
  else               { src = (sp ? p.sWout : p.tWout) + bi * 2048; o = f - 8192; }
  ((h2*)dst)[i] = pkrtz(src[o], src[o + 1]);
}

// ---------------- embed + input rmsnorm (writes fp16 X) ----------------
__global__ __launch_bounds__(256) void embed_kernel(
    const float* __restrict__ obs, const float* __restrict__ Wval,
    const float* __restrict__ bval, const float* __restrict__ innw,
    const float* __restrict__ dimemb, const float* __restrict__ cls,
    _Float16* __restrict__ X) {
  int tok = blockIdx.x * 8 + (threadIdx.x >> 5);
  int e = threadIdx.x & 31;
  const int total = B_ * T_ * SLOTS_;
  if (tok >= total) return;
  int slot = tok % SLOTS_;
  int bt = tok / SLOTS_;
  float v;
  if (slot < OBS_) {
    float o = obs[bt * OBS_ + slot];
    v = o * Wval[e] + bval[e] + dimemb[slot * E_ + e];
  } else {
    v = cls[(slot - OBS_) * E_ + e];
  }
  float ss = red32(v * v);
  X[tok * E_ + e] = (_Float16)(v * rsqrtf(ss * (1.0f / E_) + 1e-6f) * innw[e]);
}

// ================= full attention block, all GEMM-shaped math on MFMA ======
// SV = valid rows, SP = padded rows (multiple of 16).
// LDS (halves): [hb SP*32 | qb SP*32 | kb SP*32 | vT 32*VSTRIDE].
//   hb: h -> (wave-private P scratch during attention) -> o -> h2
//   ffnb (SV*64) overlays qb+kb ; ao scratch = qb ; out scratch = vT region.
// Spatial: 2 sequences as one 134-row slab; seq separation via score mask.
template <int SV, int SP, bool TEMPORAL>
__device__ __forceinline__ void block_body(
    _Float16* __restrict__ X, const _Float16* __restrict__ W16,
    const float* __restrict__ norm4, const float* __restrict__ qkn, int bid) {
  constexpr int SREG = (SV + 7) / 8;
  constexpr int MT = SP / 16;
  constexpr int VSTRIDE = TEMPORAL ? 136 : 168;  // bank-spread padded [d][s]
  __shared__ __align__(16) _Float16 smem[SP * 96 + 32 * VSTRIDE];
  _Float16* hb = smem;
  _Float16* qb = smem + SP * 32;
  _Float16* kb = smem + SP * 64;
  _Float16* vT = smem + SP * 96;   // [d][s] transposed V
  _Float16* ffnb = qb;             // ffn overlay (SV*64 over qb+kb)
  _Float16* aob = qb;              // ao scratch
  _Float16* outb = vT;             // out scratch (SP*32 <= 32*VSTRIDE)

  const int tid = threadIdx.x;
  const int e = tid & 31, srow = tid >> 5;
  const int l = tid & 63, wv = tid >> 6;
  const int lm = l & 15, lq = l >> 4, hd = l & 7;

  int base, stride;
  if (TEMPORAL) {
    int b = bid / SLOTS_;
    int slot = bid % SLOTS_;
    base = (b * T_ * SLOTS_ + slot) * E_;
    stride = SLOTS_ * E_;
  } else {
    base = bid * 2 * SLOTS_ * E_;  // contiguous 134-row slab
    stride = E_;
  }

  const float nw0 = norm4[e], nw1 = norm4[E_ + e], nw2 = norm4[2 * E_ + e],
              nw3 = norm4[3 * E_ + e];
  const fx4 fz = {0.f, 0.f, 0.f, 0.f};
  const float qw = qkn[hd], kw = qkn[8 + hd];
  const float qscale = 0.35355339059327373f * 1.4426950408889634f;  // 1/sqrt(8)*log2e
  float theta = 0.f;
  if (TEMPORAL) theta = exp2f(-(float)(hd & 3) * 3.3219280948873623f);

  // ---- phase 1: x -> regs (all loads first, then process) ----
  float xr[SREG];
#pragma unroll
  for (int k = 0; k < SREG; k++) {
    int r = srow + 8 * k;
    if (SV % 8 == 0 || r < SV) xr[k] = (float)X[base + r * stride + e];
  }
#pragma unroll
  for (int k = 0; k < SREG; k++) {
    int r = srow + 8 * k;
    if (SV % 8 == 0 || r < SV) {
      float ss = red32(xr[k] * xr[k]);
      hb[r * 32 + e] = (_Float16)(xr[k] * rsqrtf(ss * (1.0f / E_) + 1e-6f) * nw0);
    }
  }
  __syncthreads();

  // ---- phase 2: q/k/v = MFMA(h, W) + head rmsnorm + RoPE; v -> vT ----
  for (int u = wv; u < MT * 2; u += 4) {
    const int mt = u >> 1, nt = u & 1;
    h8 aH = *(const h8*)(hb + (mt * 16 + lm) * 32 + lq * 8);
    float rc[4], rs[4];
    if (TEMPORAL) {
#pragma unroll
      for (int r = 0; r < 4; r++) {
        float ang = (float)(mt * 16 + lq * 4 + r) * theta;
        __sincosf(ang, &rs[r], &rc[r]);
      }
    }
    const int d = nt * 16 + lm;
    h8 bq = *(const h8*)(W16 + (nt * 16 + lm) * 32 + lq * 8);
    h8 bk = *(const h8*)(W16 + 1024 + (nt * 16 + lm) * 32 + lq * 8);
    h8 bv = *(const h8*)(W16 + 2048 + (nt * 16 + lm) * 32 + lq * 8);
    fx4 aq = mfma16(aH, bq, fz);
    fx4 ak = mfma16(aH, bk, fz);
    fx4 av = mfma16(aH, bv, fz);
#pragma unroll
    for (int r = 0; r < 4; r++) {
      int s = mt * 16 + lq * 4 + r;
      float q1 = aq[r], k1 = ak[r];
      float qv = q1 * rsqrtf(red8(q1 * q1) * 0.125f + 1e-6f) * qw;
      float kv = k1 * rsqrtf(red8(k1 * k1) * 0.125f + 1e-6f) * kw;
      if (TEMPORAL) {
        float qp = __shfl_xor(qv, 4);
        float kp = __shfl_xor(kv, 4);
        qv = (hd < 4) ? (qv * rc[r] - qp * rs[r]) : (qv * rc[r] + qp * rs[r]);
        kv = (hd < 4) ? (kv * rc[r] - kp * rs[r]) : (kv * rc[r] + kp * rs[r]);
      }
      if (SV == SP || s < SV) {
        qb[s * 32 + d] = (_Float16)(qv * qscale);  // exp2-ready
        kb[s * 32 + d] = (_Float16)kv;
      }
    }
    // v -> vT[d][s], packed pairs (cols s0..s0+3)
    const int s0 = mt * 16 + lq * 4;
    if (SV == SP || s0 + 1 < SV)
      *(h2*)(vT + d * VSTRIDE + s0) = pkrtz(av[0], av[1]);
    if (SV == SP || s0 + 3 < SV)
      *(h2*)(vT + d * VSTRIDE + s0 + 2) = pkrtz(av[2], av[3]);
  }
  if (!TEMPORAL) {
    // zero vT cols [134,160) so padded-K PV chunks multiply P*0 (finite)
    for (int idx = tid; idx < 32 * 13; idx += 256) {
      int d = idx / 13, c = 2 * SLOTS_ + 2 * (idx % 13);
      *(h2*)(vT + d * VSTRIDE + c) = pkrtz(0.f, 0.f);
    }
  }
  __syncthreads();

  // ---- phase 3: MFMA attention ----
  // unit u = head*MT + mt; wave handles u ≡ wv (mod 4) -> MT units/wave.
  // QK^T: A = q rows (all dims), B = K rows masked to head (quad lq == h).
  // P chunk (16q x 32k fp16) in wave-private hb region; PV: B = vT rows.
  {
    constexpr int NT = SP / 16;
    constexpr int NPAIR = (NT + 1) / 2;
    float oreg[MT][4];
    _Float16* psc = hb + wv * 512;  // wave-private 16x32 chunk
    const h8 z8 = {};
#pragma unroll
    for (int ui = 0; ui < MT; ui++) {
      const int u = wv + ui * 4;
      const int h = u / MT;
      const int mt = u % MT;
      h8 aQ = *(const h8*)(qb + (mt * 16 + lm) * 32 + lq * 8);
      bool rs0[4];
      if (!TEMPORAL) {
#pragma unroll
        for (int r = 0; r < 4; r++) rs0[r] = (mt * 16 + lq * 4 + r) < SLOTS_;
      }
      fx4 oacc = fz;
      float lsum[4] = {0.f, 0.f, 0.f, 0.f};
#pragma unroll
      for (int p = 0; p < NPAIR; p++) {
#pragma unroll
        for (int hf = 0; hf < 2; hf++) {
          const int nt = 2 * p + hf;
          if (nt < NT) {
            h8 bK = *(const h8*)(kb + (nt * 16 + lm) * 32 + lq * 8);
            bK = (lq == h) ? bK : z8;  // mask to head h dims
            fx4 sc = mfma16(aQ, bK, fz);
            const int col = nt * 16 + lm;
            bool cv = true, cs = false;
            if (!TEMPORAL) { cv = col < 2 * SLOTS_; cs = col < SLOTS_; }
#pragma unroll
            for (int r = 0; r < 4; r++) {
              float ev = __builtin_amdgcn_exp2f(sc[r]);
              if (!TEMPORAL) ev = (cv && (rs0[r] == cs)) ? ev : 0.f;
              lsum[r] += ev;
              psc[(lq * 4 + r) * 32 + hf * 16 + lm] = (_Float16)ev;
            }
          } else {
#pragma unroll
            for (int r = 0; r < 4; r++)
              psc[(lq * 4 + r) * 32 + 16 + lm] = (_Float16)0.f;
          }
        }
        h8 aP = *(const h8*)(psc + lm * 32 + lq * 8);
        const int dv = h * 8 + (lm & 7);  // lm>=8 duplicates; C cols >=8 unused
        h8 bV = *(const h8*)(vT + dv * VSTRIDE + p * 32 + lq * 8);
        oacc = mfma16(aP, bV, oacc);
      }
#pragma unroll
      for (int r = 0; r < 4; r++) {
        float lv = lsum[r];
        lv += __shfl_xor(lv, 1); lv += __shfl_xor(lv, 2);
        lv += __shfl_xor(lv, 4); lv += __shfl_xor(lv, 8);
        oreg[ui][r] = oacc[r] / lv;
      }
    }
    __syncthreads();  // all psc use done before o overwrites hb
#pragma unroll
    for (int ui = 0; ui < MT; ui++) {
      const int u = wv + ui * 4;
      const int h = u / MT;
      const int mt = u % MT;
      if (lm < 8) {
#pragma unroll
        for (int r = 0; r < 4; r++)
          hb[(mt * 16 + lq * 4 + r) * 32 + h * 8 + lm] = (_Float16)oreg[ui][r];
      }
    }
  }
  __syncthreads();

  // ---- phase 4: ao = MFMA(o, Wo) -> aob (fp16) ----
  for (int u = wv; u < MT * 2; u += 4) {
    const int mt = u >> 1, nt = u & 1;
    h8 aO = *(const h8*)(hb + (mt * 16 + lm) * 32 + lq * 8);
    h8 bo = *(const h8*)(W16 + 3072 + (nt * 16 + lm) * 32 + lq * 8);
    fx4 acc = mfma16(aO, bo, fz);
#pragma unroll
    for (int r = 0; r < 4; r++) {
      int s = mt * 16 + lq * 4 + r;
      if (SV == SP || s < SV) aob[s * 32 + nt * 16 + lm] = (_Float16)acc[r];
    }
  }
  __syncthreads();
  // ---- phase 4 epilogue: x += rms(ao); h2 = rms(x) -> hb ----
#pragma unroll
  for (int k = 0; k < SREG; k++) {
    int r = srow + 8 * k;
    if (SV % 8 == 0 || r < SV) {
      float a = (float)aob[r * 32 + e];
      float ss = red32(a * a);
      xr[k] += a * rsqrtf(ss * (1.0f / E_) + 1e-6f) * nw1;
      float hx = xr[k];
      float s2 = red32(hx * hx);
      hb[r * 32 + e] = (_Float16)(hx * rsqrtf(s2 * (1.0f / E_) + 1e-6f) * nw2);
    }
  }
  __syncthreads();

  // ---- phase 5: ffn = silu(MFMA(h2,Wg)) * MFMA(h2,Wvl) -> ffnb ----
  for (int u = wv; u < MT * 4; u += 4) {
    const int mt = u >> 2, nt = u & 3;
    h8 aH2 = *(const h8*)(hb + (mt * 16 + lm) * 32 + lq * 8);
    h8 bg = *(const h8*)(W16 + 4096 + (nt * 16 + lm) * 32 + lq * 8);
    h8 bl = *(const h8*)(W16 + 6144 + (nt * 16 + lm) * 32 + lq * 8);
    fx4 g = mfma16(aH2, bg, fz);
    fx4 vvv = mfma16(aH2, bl, fz);
#pragma unroll
    for (int r = 0; r < 4; r++) {
      int s = mt * 16 + lq * 4 + r;
      if (SV == SP || s < SV) {
        float gg = g[r];
        float sg = gg / (1.0f + __expf(-gg));
        ffnb[s * 64 + nt * 16 + lm] = (_Float16)(sg * vvv[r]);
      }
    }
  }
  __syncthreads();

  // ---- phase 6: out = MFMA(ffn, Wout^T) [K=64 via 2 chained] -> outb ----
  for (int u = wv; u < MT * 2; u += 4) {
    const int mt = u >> 1, nt = u & 1;
    h8 a0 = *(const h8*)(ffnb + (mt * 16 + lm) * 64 + lq * 8);
    h8 a1 = *(const h8*)(ffnb + (mt * 16 + lm) * 64 + 32 + lq * 8);
    h8 b0 = *(const h8*)(W16 + 8192 + (nt * 16 + lm) * 64 + lq * 8);
    h8 b1 = *(const h8*)(W16 + 8192 + (nt * 16 + lm) * 64 + 32 + lq * 8);
    fx4 acc = mfma16(a1, b1, mfma16(a0, b0, fz));
#pragma unroll
    for (int r = 0; r < 4; r++) {
      int s = mt * 16 + lq * 4 + r;
      if (SV == SP || s < SV) outb[s * 32 + nt * 16 + lm] = (_Float16)acc[r];
    }
  }
  __syncthreads();
  // ---- phase 6 epilogue: x += rms(out), store fp16 ----
#pragma unroll
  for (int k = 0; k < SREG; k++) {
    int r = srow + 8 * k;
    if (SV % 8 == 0 || r < SV) {
      float a = (float)outb[r * 32 + e];
      float ss = red32(a * a);
      xr[k] += a * rsqrtf(ss * (1.0f / E_) + 1e-6f) * nw3;
      X[base + r * stride + e] = (_Float16)xr[k];
    }
  }
}

__global__ __launch_bounds__(256, 4) void attn_spatial_kernel(
    _Float16* __restrict__ X, const _Float16* __restrict__ W16,
    const float* __restrict__ norm4, const float* __restrict__ qkn) {
  block_body<2 * SLOTS_, 144, false>(X, W16, norm4, qkn, blockIdx.x);
}

__global__ __launch_bounds__(256, 4) void attn_temporal_kernel(
    _Float16* __restrict__ X, const _Float16* __restrict__ W16,
    const float* __restrict__ norm4, const float* __restrict__ qkn) {
  block_body<T_, 128, true>(X, W16, norm4, qkn, blockIdx.x);
}

// ---------------- final norm + output extraction ----------------
__global__ __launch_bounds__(256) void final_kernel(const _Float16* __restrict__ X,
                                                    const float* __restrict__ fnw,
                                                    float* __restrict__ out) {
  int tok = blockIdx.x * 8 + (threadIdx.x >> 5);
  int e = threadIdx.x & 31;
  if (tok >= B_ * 3) return;
  int b = tok / 3, j = tok % 3;
  const _Float16* xp = X + ((size_t)(b * T_ + (T_ - 1)) * SLOTS_ + OBS_ + j) * E_;
  float v = (float)xp[e];
  float ss = red32(v * v);
  out[j * (B_ * E_) + b * E_ + e] = v * rsqrtf(ss * (1.0f / E_) + 1e-6f) * fnw[e];
}

extern "C" void kernel_launch(void* const* d_in, const int* in_sizes, int n_in,
                              void* d_out, int out_size, void* d_ws, size_t ws_size,
                              hipStream_t stream) {
  (void)in_sizes; (void)n_in; (void)out_size; (void)ws_size;
  const float* obs          = (const float*)d_in[0];
  const float* W_val        = (const float*)d_in[1];
  const float* b_val        = (const float*)d_in[2];
  const float* input_norm_w = (const float*)d_in[3];
  const float* dim_embed    = (const float*)d_in[4];
  const float* cls_tokens   = (const float*)d_in[5];
  const float* final_norm_w = (const float*)d_in[6];
  const float* s_n4   = (const float*)d_in[14];
  const float* s_qkn  = (const float*)d_in[15];
  const float* t_n4   = (const float*)d_in[23];
  const float* t_qkn  = (const float*)d_in[24];

  _Float16* X = (_Float16*)d_ws;  // fp16 residual stream, 8.78 MB
  _Float16* W16 = (_Float16*)((char*)d_ws + X16_BYTES);  // 5*10240 halves
  float* out = (float*)d_out;

  WPtrs wp;
  wp.sWq   = (const float*)d_in[7];
  wp.sWk   = (const float*)d_in[8];
  wp.sWv   = (const float*)d_in[9];
  wp.sWo   = (const float*)d_in[10];
  wp.sWg   = (const float*)d_in[11];
  wp.sWvl  = (const float*)d_in[12];
  wp.sWout = (const float*)d_in[13];
  wp.tWq   = (const float*)d_in[16];
  wp.tWk   = (const float*)d_in[17];
  wp.tWv   = (const float*)d_in[18];
  wp.tWo   = (const float*)d_in[19];
  wp.tWg   = (const float*)d_in[20];
  wp.tWvl  = (const float*)d_in[21];
  wp.tWout = (const float*)d_in[22];
  cvt_weights_kernel<<<100, 256, 0, stream>>>(wp, W16);

  const int total_tokens = B_ * T_ * SLOTS_;
  embed_kernel<<<(total_tokens + 7) / 8, 256, 0, stream>>>(
      obs, W_val, b_val, input_norm_w, dim_embed, cls_tokens, X);

  const int N4 = 4 * E_;   // 128
  const int QN = 2 * HD_;  // 16

#define SPATIAL(i)                                                     \
  attn_spatial_kernel<<<B_ * T_ / 2, 256, 0, stream>>>(                \
      X, W16 + (i)*WBLK, s_n4 + (i)*N4, s_qkn + (i)*QN)
#define TEMPORAL(i)                                                    \
  attn_temporal_kernel<<<B_ * SLOTS_, 256, 0, stream>>>(               \
      X, W16 + (3 + (i)) * WBLK, t_n4 + (i)*N4, t_qkn + (i)*QN)

  SPATIAL(0);
  TEMPORAL(0);
  SPATIAL(1);
  TEMPORAL(1);
  SPATIAL(2);

#undef SPATIAL
#undef TEMPORAL

  final_kernel<<<6, 256, 0, stream>>>(X, final_norm_w, out);
}

// Round 14
// 386.879 us; speedup vs baseline: 1.4653x; 1.4653x over previous
//
#include <hip/hip_runtime.h>

#define B_ 16
#define T_ 128
#define OBS_ 64
#define SLOTS_ 67
#define E_ 32
#define H_ 4
#define HD_ 8
#define FFN_ 64

typedef _Float16 h2 __attribute__((ext_vector_type(2)));
typedef _Float16 h4 __attribute__((ext_vector_type(4)));
typedef _Float16 h8 __attribute__((ext_vector_type(8)));
typedef __fp16 mh4 __attribute__((ext_vector_type(4)));
typedef __fp16 mh8 __attribute__((ext_vector_type(8)));
typedef float fx4 __attribute__((ext_vector_type(4)));
union H4u { h4 v; h2 h[2]; };

// fp16 weight block layout (halves): Wq 0 | Wk 1024 | Wv 2048 | Wo 3072 |
// Wg 4096 | Wvl 6144 | Wout 8192  (10240 halves per transformer block)
#define WBLK 10240
#define X16_BYTES (B_ * T_ * SLOTS_ * E_ * 2)  // 8,781,824 (X stored fp16)

__device__ __forceinline__ float red32(float v) {
  v += __shfl_xor(v, 16); v += __shfl_xor(v, 8); v += __shfl_xor(v, 4);
  v += __shfl_xor(v, 2);  v += __shfl_xor(v, 1);
  return v;
}
__device__ __forceinline__ float red8(float v) {
  v += __shfl_xor(v, 4); v += __shfl_xor(v, 2); v += __shfl_xor(v, 1);
  return v;
}
__device__ __forceinline__ h2 pkrtz(float x, float y) {
  return __builtin_bit_cast(h2, __builtin_amdgcn_cvt_pkrtz(x, y));
}
__device__ __forceinline__ fx4 mfma16(h8 a, h8 b, fx4 c) {
  return __builtin_amdgcn_mfma_f32_16x16x32_f16(
      __builtin_bit_cast(mh8, a), __builtin_bit_cast(mh8, b), c, 0, 0, 0);
}
__device__ __forceinline__ fx4 mfma16k16(h4 a, h4 b, fx4 c) {
  return __builtin_amdgcn_mfma_f32_16x16x16f16(
      __builtin_bit_cast(mh4, a), __builtin_bit_cast(mh4, b), c, 0, 0, 0);
}

// ---------------- weight pre-conversion to fp16 ----------------
struct WPtrs {
  const float *sWq, *sWk, *sWv, *sWo, *sWg, *sWvl, *sWout;
  const float *tWq, *tWk, *tWv, *tWo, *tWg, *tWvl, *tWout;
};

__global__ __launch_bounds__(256) void cvt_weights_kernel(WPtrs p, _Float16* dst) {
  int i = blockIdx.x * 256 + threadIdx.x;  // pair index
  const int total_pairs = 5 * WBLK / 2;    // 25600
  if (i >= total_pairs) return;
  int blk = i / (WBLK / 2);
  int f = (i % (WBLK / 2)) * 2;
  bool sp = blk < 3;
  int bi = sp ? blk : blk - 3;
  const float* src;
  int o;
  if (f < 1024)      { src = (sp ? p.sWq : p.tWq) + bi * 1024;  o = f; }
  else if (f < 2048) { src = (sp ? p.sWk : p.tWk) + bi * 1024;  o = f - 1024; }
  else if (f < 3072) { src = (sp ? p.sWv : p.tWv) + bi * 1024;  o = f - 2048; }
  else if (f < 4096) { src = (sp ? p.sWo : p.tWo) + bi * 1024;  o = f - 3072; }
  else if (f < 6144) { src = (sp ? p.sWg : p.tWg) + bi * 2048;  o = f - 4096; }
  else if (f < 8192) { src = (sp ? p.sWvl : p.tWvl) + bi * 2048; o = f - 6144; }
  else               { src = (sp ? p.sWout : p.tWout) + bi * 2048; o = f - 8192; }
  ((h2*)dst)[i] = pkrtz(src[o], src[o + 1]);
}

// ---------------- embed + input rmsnorm (writes fp16 X) ----------------
__global__ __launch_bounds__(256) void embed_kernel(
    const float* __restrict__ obs, const float* __restrict__ Wval,
    const float* __restrict__ bval, const float* __restrict__ innw,
    const float* __restrict__ dimemb, const float* __restrict__ cls,
    _Float16* __restrict__ X) {
  int tok = blockIdx.x * 8 + (threadIdx.x >> 5);
  int e = threadIdx.x & 31;
  const int total = B_ * T_ * SLOTS_;
  if (tok >= total) return;
  int slot = tok % SLOTS_;
  int bt = tok / SLOTS_;
  float v;
  if (slot < OBS_) {
    float o = obs[bt * OBS_ + slot];
    v = o * Wval[e] + bval[e] + dimemb[slot * E_ + e];
  } else {
    v = cls[(slot - OBS_) * E_ + e];
  }
  float ss = red32(v * v);
  X[tok * E_ + e] = (_Float16)(v * rsqrtf(ss * (1.0f / E_) + 1e-6f) * innw[e]);
}

// ================= full attention block, all GEMM-shaped math on MFMA ======
// SV = valid rows, SP = padded rows (multiple of 16).
// LDS (halves): [hb SP*32 | qb SP*32 | kb SP*32 | vT 32*VSTRIDE].
//   hb: h -> o -> h2 ; ffnb (SV*64) overlays qb+kb ; ao scratch = qb ;
//   out scratch = vT region.
// Attention uses the S^T formulation: S^T = K_masked · Q^T via 16x16x32 MFMA;
// exp'd C-frag of S^T is exactly the B-operand of 16x16x16 MFMA for PV
// (O^T = vT · P^T) -> no LDS P round-trip, no deferred registers.
template <int SV, int SP, bool TEMPORAL>
__device__ __forceinline__ void block_body(
    _Float16* __restrict__ X, const _Float16* __restrict__ W16,
    const float* __restrict__ norm4, const float* __restrict__ qkn, int bid) {
  constexpr int SREG = (SV + 7) / 8;
  constexpr int MT = SP / 16;
  constexpr int VSTRIDE = TEMPORAL ? 136 : 168;  // 68/84 dwords ≡ 4 (mod 32)
  __shared__ __align__(16) _Float16 smem[SP * 96 + 32 * VSTRIDE];
  _Float16* hb = smem;
  _Float16* qb = smem + SP * 32;
  _Float16* kb = smem + SP * 64;
  _Float16* vT = smem + SP * 96;   // [d][s] transposed V
  _Float16* ffnb = qb;             // ffn overlay (SV*64 over qb+kb)
  _Float16* aob = qb;              // ao scratch
  _Float16* outb = vT;             // out scratch (SP*32 <= 32*VSTRIDE)

  const int tid = threadIdx.x;
  const int e = tid & 31, srow = tid >> 5;
  const int l = tid & 63, wv = tid >> 6;
  const int lm = l & 15, lq = l >> 4, hd = l & 7;

  int base, stride;
  if (TEMPORAL) {
    int b = bid / SLOTS_;
    int slot = bid % SLOTS_;
    base = (b * T_ * SLOTS_ + slot) * E_;
    stride = SLOTS_ * E_;
  } else {
    base = bid * 2 * SLOTS_ * E_;  // contiguous 134-row slab
    stride = E_;
  }

  const float nw0 = norm4[e], nw1 = norm4[E_ + e], nw2 = norm4[2 * E_ + e],
              nw3 = norm4[3 * E_ + e];
  const fx4 fz = {0.f, 0.f, 0.f, 0.f};
  const float qw = qkn[hd], kw = qkn[8 + hd];
  const float qscale = 0.35355339059327373f * 1.4426950408889634f;  // 1/sqrt(8)*log2e
  float theta = 0.f;
  if (TEMPORAL) theta = exp2f(-(float)(hd & 3) * 3.3219280948873623f);

  // ---- phase 1: x -> regs (all loads first, then process) ----
  float xr[SREG];
#pragma unroll
  for (int k = 0; k < SREG; k++) {
    int r = srow + 8 * k;
    if (SV % 8 == 0 || r < SV) xr[k] = (float)X[base + r * stride + e];
  }
#pragma unroll
  for (int k = 0; k < SREG; k++) {
    int r = srow + 8 * k;
    if (SV % 8 == 0 || r < SV) {
      float ss = red32(xr[k] * xr[k]);
      hb[r * 32 + e] = (_Float16)(xr[k] * rsqrtf(ss * (1.0f / E_) + 1e-6f) * nw0);
    }
  }
  __syncthreads();

  // ---- phase 2: q/k/v = MFMA(h, W) + head rmsnorm + RoPE; v -> vT ----
  for (int u = wv; u < MT * 2; u += 4) {
    const int mt = u >> 1, nt = u & 1;
    h8 aH = *(const h8*)(hb + (mt * 16 + lm) * 32 + lq * 8);
    float rc[4], rs[4];
    if (TEMPORAL) {
#pragma unroll
      for (int r = 0; r < 4; r++) {
        float ang = (float)(mt * 16 + lq * 4 + r) * theta;
        __sincosf(ang, &rs[r], &rc[r]);
      }
    }
    const int d = nt * 16 + lm;
    h8 bq = *(const h8*)(W16 + (nt * 16 + lm) * 32 + lq * 8);
    h8 bk = *(const h8*)(W16 + 1024 + (nt * 16 + lm) * 32 + lq * 8);
    h8 bv = *(const h8*)(W16 + 2048 + (nt * 16 + lm) * 32 + lq * 8);
    fx4 aq = mfma16(aH, bq, fz);
    fx4 ak = mfma16(aH, bk, fz);
    fx4 av = mfma16(aH, bv, fz);
#pragma unroll
    for (int r = 0; r < 4; r++) {
      int s = mt * 16 + lq * 4 + r;
      float q1 = aq[r], k1 = ak[r];
      float qv = q1 * rsqrtf(red8(q1 * q1) * 0.125f + 1e-6f) * qw;
      float kv = k1 * rsqrtf(red8(k1 * k1) * 0.125f + 1e-6f) * kw;
      if (TEMPORAL) {
        float qp = __shfl_xor(qv, 4);
        float kp = __shfl_xor(kv, 4);
        qv = (hd < 4) ? (qv * rc[r] - qp * rs[r]) : (qv * rc[r] + qp * rs[r]);
        kv = (hd < 4) ? (kv * rc[r] - kp * rs[r]) : (kv * rc[r] + kp * rs[r]);
      }
      if (SV == SP || s < SV) {
        qb[s * 32 + d] = (_Float16)(qv * qscale);  // exp2-ready
        kb[s * 32 + d] = (_Float16)kv;
      }
    }
    // v -> vT[d][s], packed pairs (cols s0..s0+3)
    const int s0 = mt * 16 + lq * 4;
    if (SV == SP || s0 + 1 < SV)
      *(h2*)(vT + d * VSTRIDE + s0) = pkrtz(av[0], av[1]);
    if (SV == SP || s0 + 3 < SV)
      *(h2*)(vT + d * VSTRIDE + s0 + 2) = pkrtz(av[2], av[3]);
  }
  if (!TEMPORAL) {
    // zero vT cols [134,160) so padded-K PV chunks multiply P(=0)*0 (finite)
    for (int idx = tid; idx < 32 * 13; idx += 256) {
      int d = idx / 13, c = 2 * SLOTS_ + 2 * (idx % 13);
      *(h2*)(vT + d * VSTRIDE + c) = pkrtz(0.f, 0.f);
    }
  }
  __syncthreads();

  // ---- phase 3: MFMA attention, S^T formulation ----
  // wave wv = head h; loop q-tiles mt. Per k-tile:
  //   S^T tile = mfma16x16x32(A=K rows masked to quad h, B=Q rows of mt)
  //   lane holds S^T[kt*16+lq*4+r][mt*16+lm] -> exp2 -> pT = B-frag of
  //   mfma16x16x16 PV: O^T[d][q] += vT[d][k]*P[q][k]. O^T C-frag: lane
  //   holds O^T[lq*4+r][lm]; lanes lq<2 (d 0..7) write o; lq>=2 duplicate.
  {
    constexpr int NT = SP / 16;
    const int h = wv;
    const h8 z8 = {};
    const _Float16* vrow = vT + (h * 8 + (lm & 7)) * VSTRIDE;
    for (int mt = 0; mt < MT; mt++) {
      h8 bQ = *(const h8*)(qb + (mt * 16 + lm) * 32 + lq * 8);
      const int q = mt * 16 + lm;
      fx4 oaccT = fz;
      float lsum = 0.f;
#pragma unroll
      for (int kt = 0; kt < NT; kt++) {
        h8 aK = *(const h8*)(kb + (kt * 16 + lm) * 32 + lq * 8);
        aK = (lq == h) ? aK : z8;  // keep head-h dims only
        fx4 sc = mfma16(aK, bQ, fz);
        float ev[4];
#pragma unroll
        for (int r = 0; r < 4; r++) {
          float x = __builtin_amdgcn_exp2f(sc[r]);
          if (!TEMPORAL) {
            int kidx = kt * 16 + lq * 4 + r;
            bool ok = (kidx < 2 * SLOTS_) && (q < 2 * SLOTS_) &&
                      ((kidx < SLOTS_) == (q < SLOTS_));
            x = ok ? x : 0.f;
          }
          ev[r] = x;
          lsum += x;
        }
        H4u pT;
        pT.h[0] = pkrtz(ev[0], ev[1]);
        pT.h[1] = pkrtz(ev[2], ev[3]);
        h4 aV = *(const h4*)(vrow + kt * 16 + lq * 4);
        oaccT = mfma16k16(aV, pT.v, oaccT);
      }
      lsum += __shfl_xor(lsum, 16);
      lsum += __shfl_xor(lsum, 32);
      float inv = 1.0f / lsum;
      if (lq < 2 && (SV == SP || q < SV)) {
        H4u ov;
        ov.h[0] = pkrtz(oaccT[0] * inv, oaccT[1] * inv);
        ov.h[1] = pkrtz(oaccT[2] * inv, oaccT[3] * inv);
        *(h4*)(hb + q * 32 + h * 8 + lq * 4) = ov.v;  // h dead -> o
      }
    }
  }
  __syncthreads();

  // ---- phase 4: ao = MFMA(o, Wo) -> aob (fp16) ----
  for (int u = wv; u < MT * 2; u += 4) {
    const int mt = u >> 1, nt = u & 1;
    h8 aO = *(const h8*)(hb + (mt * 16 + lm) * 32 + lq * 8);
    h8 bo = *(const h8*)(W16 + 3072 + (nt * 16 + lm) * 32 + lq * 8);
    fx4 acc = mfma16(aO, bo, fz);
#pragma unroll
    for (int r = 0; r < 4; r++) {
      int s = mt * 16 + lq * 4 + r;
      if (SV == SP || s < SV) aob[s * 32 + nt * 16 + lm] = (_Float16)acc[r];
    }
  }
  __syncthreads();
  // ---- phase 4 epilogue: x += rms(ao); h2 = rms(x) -> hb ----
#pragma unroll
  for (int k = 0; k < SREG; k++) {
    int r = srow + 8 * k;
    if (SV % 8 == 0 || r < SV) {
      float a = (float)aob[r * 32 + e];
      float ss = red32(a * a);
      xr[k] += a * rsqrtf(ss * (1.0f / E_) + 1e-6f) * nw1;
      float hx = xr[k];
      float s2 = red32(hx * hx);
      hb[r * 32 + e] = (_Float16)(hx * rsqrtf(s2 * (1.0f / E_) + 1e-6f) * nw2);
    }
  }
  __syncthreads();

  // ---- phase 5: ffn = silu(MFMA(h2,Wg)) * MFMA(h2,Wvl) -> ffnb ----
  for (int u = wv; u < MT * 4; u += 4) {
    const int mt = u >> 2, nt = u & 3;
    h8 aH2 = *(const h8*)(hb + (mt * 16 + lm) * 32 + lq * 8);
    h8 bg = *(const h8*)(W16 + 4096 + (nt * 16 + lm) * 32 + lq * 8);
    h8 bl = *(const h8*)(W16 + 6144 + (nt * 16 + lm) * 32 + lq * 8);
    fx4 g = mfma16(aH2, bg, fz);
    fx4 vvv = mfma16(aH2, bl, fz);
#pragma unroll
    for (int r = 0; r < 4; r++) {
      int s = mt * 16 + lq * 4 + r;
      if (SV == SP || s < SV) {
        float gg = g[r];
        float sg = gg / (1.0f + __expf(-gg));
        ffnb[s * 64 + nt * 16 + lm] = (_Float16)(sg * vvv[r]);
      }
    }
  }
  __syncthreads();

  // ---- phase 6: out = MFMA(ffn, Wout^T) [K=64 via 2 chained] -> outb ----
  for (int u = wv; u < MT * 2; u += 4) {
    const int mt = u >> 1, nt = u & 1;
    h8 a0 = *(const h8*)(ffnb + (mt * 16 + lm) * 64 + lq * 8);
    h8 a1 = *(const h8*)(ffnb + (mt * 16 + lm) * 64 + 32 + lq * 8);
    h8 b0 = *(const h8*)(W16 + 8192 + (nt * 16 + lm) * 64 + lq * 8);
    h8 b1 = *(const h8*)(W16 + 8192 + (nt * 16 + lm) * 64 + 32 + lq * 8);
    fx4 acc = mfma16(a1, b1, mfma16(a0, b0, fz));
#pragma unroll
    for (int r = 0; r < 4; r++) {
      int s = mt * 16 + lq * 4 + r;
      if (SV == SP || s < SV) outb[s * 32 + nt * 16 + lm] = (_Float16)acc[r];
    }
  }
  __syncthreads();
  // ---- phase 6 epilogue: x += rms(out), store fp16 ----
#pragma unroll
  for (int k = 0; k < SREG; k++) {
    int r = srow + 8 * k;
    if (SV % 8 == 0 || r < SV) {
      float a = (float)outb[r * 32 + e];
      float ss = red32(a * a);
      xr[k] += a * rsqrtf(ss * (1.0f / E_) + 1e-6f) * nw3;
      X[base + r * stride + e] = (_Float16)xr[k];
    }
  }
}

__global__ __launch_bounds__(256, 4) void attn_spatial_kernel(
    _Float16* __restrict__ X, const _Float16* __restrict__ W16,
    const float* __restrict__ norm4, const float* __restrict__ qkn) {
  block_body<2 * SLOTS_, 144, false>(X, W16, norm4, qkn, blockIdx.x);
}

__global__ __launch_bounds__(256, 4) void attn_temporal_kernel(
    _Float16* __restrict__ X, const _Float16* __restrict__ W16,
    const float* __restrict__ norm4, const float* __restrict__ qkn) {
  block_body<T_, 128, true>(X, W16, norm4, qkn, blockIdx.x);
}

// ---------------- final norm + output extraction ----------------
__global__ __launch_bounds__(256) void final_kernel(const _Float16* __restrict__ X,
                                                    const float* __restrict__ fnw,
                                                    float* __restrict__ out) {
  int tok = blockIdx.x * 8 + (threadIdx.x >> 5);
  int e = threadIdx.x & 31;
  if (tok >= B_ * 3) return;
  int b = tok / 3, j = tok % 3;
  const _Float16* xp = X + ((size_t)(b * T_ + (T_ - 1)) * SLOTS_ + OBS_ + j) * E_;
  float v = (float)xp[e];
  float ss = red32(v * v);
  out[j * (B_ * E_) + b * E_ + e] = v * rsqrtf(ss * (1.0f / E_) + 1e-6f) * fnw[e];
}

extern "C" void kernel_launch(void* const* d_in, const int* in_sizes, int n_in,
                              void* d_out, int out_size, void* d_ws, size_t ws_size,
                              hipStream_t stream) {
  (void)in_sizes; (void)n_in; (void)out_size; (void)ws_size;
  const float* obs          = (const float*)d_in[0];
  const float* W_val        = (const float*)d_in[1];
  const float* b_val        = (const float*)d_in[2];
  const float* input_norm_w = (const float*)d_in[3];
  const float* dim_embed    = (const float*)d_in[4];
  const float* cls_tokens   = (const float*)d_in[5];
  const float* final_norm_w = (const float*)d_in[6];
  const float* s_n4   = (const float*)d_in[14];
  const float* s_qkn  = (const float*)d_in[15];
  const float* t_n4   = (const float*)d_in[23];
  const float* t_qkn  = (const float*)d_in[24];

  _Float16* X = (_Float16*)d_ws;  // fp16 residual stream, 8.78 MB
  _Float16* W16 = (_Float16*)((char*)d_ws + X16_BYTES);  // 5*10240 halves
  float* out = (float*)d_out;

  WPtrs wp;
  wp.sWq   = (const float*)d_in[7];
  wp.sWk   = (const float*)d_in[8];
  wp.sWv   = (const float*)d_in[9];
  wp.sWo   = (const float*)d_in[10];
  wp.sWg   = (const float*)d_in[11];
  wp.sWvl  = (const float*)d_in[12];
  wp.sWout = (const float*)d_in[13];
  wp.tWq   = (const float*)d_in[16];
  wp.tWk   = (const float*)d_in[17];
  wp.tWv   = (const float*)d_in[18];
  wp.tWo   = (const float*)d_in[19];
  wp.tWg   = (const float*)d_in[20];
  wp.tWvl  = (const float*)d_in[21];
  wp.tWout = (const float*)d_in[22];
  cvt_weights_kernel<<<100, 256, 0, stream>>>(wp, W16);

  const int total_tokens = B_ * T_ * SLOTS_;
  embed_kernel<<<(total_tokens + 7) / 8, 256, 0, stream>>>(
      obs, W_val, b_val, input_norm_w, dim_embed, cls_tokens, X);

  const int N4 = 4 * E_;   // 128
  const int QN = 2 * HD_;  // 16

#define SPATIAL(i)                                                     \
  attn_spatial_kernel<<<B_ * T_ / 2, 256, 0, stream>>>(                \
      X, W16 + (i)*WBLK, s_n4 + (i)*N4, s_qkn + (i)*QN)
#define TEMPORAL(i)                                                    \
  attn_temporal_kernel<<<B_ * SLOTS_, 256, 0, stream>>>(               \
      X, W16 + (3 + (i)) * WBLK, t_n4 + (i)*N4, t_qkn + (i)*QN)

  SPATIAL(0);
  TEMPORAL(0);
  SPATIAL(1);
  TEMPORAL(1);
  SPATIAL(2);

#undef SPATIAL
#undef TEMPORAL

  final_kernel<<<6, 256, 0, stream>>>(X, final_norm_w, out);
}

// Round 15
// 374.875 us; speedup vs baseline: 1.5122x; 1.0320x over previous
//
#include <hip/hip_runtime.h>

#define B_ 16
#define T_ 128
#define OBS_ 64
#define SLOTS_ 67
#define E_ 32
#define H_ 4
#define HD_ 8
#define FFN_ 64

typedef _Float16 h2 __attribute__((ext_vector_type(2)));
typedef _Float16 h4 __attribute__((ext_vector_type(4)));
typedef _Float16 h8 __attribute__((ext_vector_type(8)));
typedef __fp16 mh4 __attribute__((ext_vector_type(4)));
typedef __fp16 mh8 __attribute__((ext_vector_type(8)));
typedef float fx4 __attribute__((ext_vector_type(4)));
union H4u { h4 v; h2 h[2]; };

// fp16 weight block layout (halves): Wq 0 | Wk 1024 | Wv 2048 | Wo 3072 |
// Wg 4096 | Wvl 6144 | Wout 8192  (10240 halves per transformer block)
#define WBLK 10240
#define X16_BYTES (B_ * T_ * SLOTS_ * E_ * 2)  // 8,781,824 (X stored fp16)

__device__ __forceinline__ float red32(float v) {
  v += __shfl_xor(v, 16); v += __shfl_xor(v, 8); v += __shfl_xor(v, 4);
  v += __shfl_xor(v, 2);  v += __shfl_xor(v, 1);
  return v;
}
__device__ __forceinline__ float red8(float v) {
  v += __shfl_xor(v, 4); v += __shfl_xor(v, 2); v += __shfl_xor(v, 1);
  return v;
}
__device__ __forceinline__ h2 pkrtz(float x, float y) {
  return __builtin_bit_cast(h2, __builtin_amdgcn_cvt_pkrtz(x, y));
}
__device__ __forceinline__ fx4 mfma16(h8 a, h8 b, fx4 c) {
  return __builtin_amdgcn_mfma_f32_16x16x32_f16(
      __builtin_bit_cast(mh8, a), __builtin_bit_cast(mh8, b), c, 0, 0, 0);
}
__device__ __forceinline__ fx4 mfma16k16(h4 a, h4 b, fx4 c) {
  return __builtin_amdgcn_mfma_f32_16x16x16f16(
      __builtin_bit_cast(mh4, a), __builtin_bit_cast(mh4, b), c, 0, 0, 0);
}

// ---------------- setup: weight fp16 conversion + embed, one kernel ----------
struct WPtrs {
  const float *sWq, *sWk, *sWv, *sWo, *sWg, *sWvl, *sWout;
  const float *tWq, *tWk, *tWv, *tWo, *tWg, *tWvl, *tWout;
};

#define CVT_BLOCKS 100

__global__ __launch_bounds__(256) void setup_kernel(
    WPtrs p, _Float16* __restrict__ dst,
    const float* __restrict__ obs, const float* __restrict__ Wval,
    const float* __restrict__ bval, const float* __restrict__ innw,
    const float* __restrict__ dimemb, const float* __restrict__ cls,
    _Float16* __restrict__ X) {
  if (blockIdx.x < CVT_BLOCKS) {
    int i = blockIdx.x * 256 + threadIdx.x;  // pair index
    const int total_pairs = 5 * WBLK / 2;    // 25600
    if (i >= total_pairs) return;
    int blk = i / (WBLK / 2);
    int f = (i % (WBLK / 2)) * 2;
    bool sp = blk < 3;
    int bi = sp ? blk : blk - 3;
    const float* src;
    int o;
    if (f < 1024)      { src = (sp ? p.sWq : p.tWq) + bi * 1024;  o = f; }
    else if (f < 2048) { src = (sp ? p.sWk : p.tWk) + bi * 1024;  o = f - 1024; }
    else if (f < 3072) { src = (sp ? p.sWv : p.tWv) + bi * 1024;  o = f - 2048; }
    else if (f < 4096) { src = (sp ? p.sWo : p.tWo) + bi * 1024;  o = f - 3072; }
    else if (f < 6144) { src = (sp ? p.sWg : p.tWg) + bi * 2048;  o = f - 4096; }
    else if (f < 8192) { src = (sp ? p.sWvl : p.tWvl) + bi * 2048; o = f - 6144; }
    else               { src = (sp ? p.sWout : p.tWout) + bi * 2048; o = f - 8192; }
    ((h2*)dst)[i] = pkrtz(src[o], src[o + 1]);
  } else {
    int tok = (blockIdx.x - CVT_BLOCKS) * 8 + (threadIdx.x >> 5);
    int e = threadIdx.x & 31;
    const int total = B_ * T_ * SLOTS_;
    if (tok >= total) return;
    int slot = tok % SLOTS_;
    int bt = tok / SLOTS_;
    float v;
    if (slot < OBS_) {
      float o = obs[bt * OBS_ + slot];
      v = o * Wval[e] + bval[e] + dimemb[slot * E_ + e];
    } else {
      v = cls[(slot - OBS_) * E_ + e];
    }
    float ss = red32(v * v);
    X[tok * E_ + e] = (_Float16)(v * rsqrtf(ss * (1.0f / E_) + 1e-6f) * innw[e]);
  }
}

// ================= full attention block, all GEMM-shaped math on MFMA ======
// SV = valid rows, SP = padded rows (multiple of 16).
// LDS (halves): [hb SP*32 | qb SP*32 | kb SP*32 | vT 32*VSTRIDE].
//   hb: h -> o -> h2 ; ffnb (SV*64) overlays qb+kb ; ao scratch = qb ;
//   out scratch = vT region.
// Attention: S^T = K_masked · Q^T (16x16x32); exp'd C-frag of S^T is the
// B-operand of 16x16x16 PV (O^T = vT · P^T) -> fully in-register.
// Spatial slab = [seq0 rows 0..66 | seq1 rows 67..133 | pad 134..143];
// phase 3 iterates only the k-tiles of the query's own sequence.
template <int SV, int SP, bool TEMPORAL>
__device__ __forceinline__ void block_body(
    _Float16* __restrict__ X, const _Float16* __restrict__ W16,
    const float* __restrict__ norm4, const float* __restrict__ qkn, int bid) {
  constexpr int SREG = (SV + 7) / 8;
  constexpr int MT = SP / 16;
  constexpr int VSTRIDE = TEMPORAL ? 136 : 168;  // 68/84 dwords ≡ 4 (mod 32)
  __shared__ __align__(16) _Float16 smem[SP * 96 + 32 * VSTRIDE];
  _Float16* hb = smem;
  _Float16* qb = smem + SP * 32;
  _Float16* kb = smem + SP * 64;
  _Float16* vT = smem + SP * 96;   // [d][s] transposed V
  _Float16* ffnb = qb;             // ffn overlay (SV*64 over qb+kb)
  _Float16* aob = qb;              // ao scratch
  _Float16* outb = vT;             // out scratch (SP*32 <= 32*VSTRIDE)

  const int tid = threadIdx.x;
  const int e = tid & 31, srow = tid >> 5;
  const int l = tid & 63, wv = tid >> 6;
  const int lm = l & 15, lq = l >> 4, hd = l & 7;

  int base, stride;
  if (TEMPORAL) {
    int b = bid / SLOTS_;
    int slot = bid % SLOTS_;
    base = (b * T_ * SLOTS_ + slot) * E_;
    stride = SLOTS_ * E_;
  } else {
    base = bid * 2 * SLOTS_ * E_;  // contiguous 134-row slab
    stride = E_;
  }

  const float nw0 = norm4[e], nw1 = norm4[E_ + e], nw2 = norm4[2 * E_ + e],
              nw3 = norm4[3 * E_ + e];
  const fx4 fz = {0.f, 0.f, 0.f, 0.f};
  const float qw = qkn[hd], kw = qkn[8 + hd];
  const float qscale = 0.35355339059327373f * 1.4426950408889634f;  // 1/sqrt(8)*log2e
  float theta = 0.f;
  if (TEMPORAL) theta = exp2f(-(float)(hd & 3) * 3.3219280948873623f);

  // ---- phase 1: x -> regs (all loads first, then process) ----
  float xr[SREG];
#pragma unroll
  for (int k = 0; k < SREG; k++) {
    int r = srow + 8 * k;
    if (SV % 8 == 0 || r < SV) xr[k] = (float)X[base + r * stride + e];
  }
#pragma unroll
  for (int k = 0; k < SREG; k++) {
    int r = srow + 8 * k;
    if (SV % 8 == 0 || r < SV) {
      float ss = red32(xr[k] * xr[k]);
      hb[r * 32 + e] = (_Float16)(xr[k] * rsqrtf(ss * (1.0f / E_) + 1e-6f) * nw0);
    }
  }
  __syncthreads();

  // ---- phase 2: q/k/v = MFMA(h, W) + head rmsnorm + RoPE; v -> vT ----
  for (int u = wv; u < MT * 2; u += 4) {
    const int mt = u >> 1, nt = u & 1;
    h8 aH = *(const h8*)(hb + (mt * 16 + lm) * 32 + lq * 8);
    float rc[4], rs[4];
    if (TEMPORAL) {
#pragma unroll
      for (int r = 0; r < 4; r++) {
        float ang = (float)(mt * 16 + lq * 4 + r) * theta;
        __sincosf(ang, &rs[r], &rc[r]);
      }
    }
    const int d = nt * 16 + lm;
    h8 bq = *(const h8*)(W16 + (nt * 16 + lm) * 32 + lq * 8);
    h8 bk = *(const h8*)(W16 + 1024 + (nt * 16 + lm) * 32 + lq * 8);
    h8 bv = *(const h8*)(W16 + 2048 + (nt * 16 + lm) * 32 + lq * 8);
    fx4 aq = mfma16(aH, bq, fz);
    fx4 ak = mfma16(aH, bk, fz);
    fx4 av = mfma16(aH, bv, fz);
#pragma unroll
    for (int r = 0; r < 4; r++) {
      int s = mt * 16 + lq * 4 + r;
      float q1 = aq[r], k1 = ak[r];
      float qv = q1 * rsqrtf(red8(q1 * q1) * 0.125f + 1e-6f) * qw;
      float kv = k1 * rsqrtf(red8(k1 * k1) * 0.125f + 1e-6f) * kw;
      if (TEMPORAL) {
        float qp = __shfl_xor(qv, 4);
        float kp = __shfl_xor(kv, 4);
        qv = (hd < 4) ? (qv * rc[r] - qp * rs[r]) : (qv * rc[r] + qp * rs[r]);
        kv = (hd < 4) ? (kv * rc[r] - kp * rs[r]) : (kv * rc[r] + kp * rs[r]);
      }
      if (SV == SP || s < SV) {
        qb[s * 32 + d] = (_Float16)(qv * qscale);  // exp2-ready
        kb[s * 32 + d] = (_Float16)kv;
      }
    }
    // v -> vT[d][s], packed pairs (cols s0..s0+3)
    const int s0 = mt * 16 + lq * 4;
    if (SV == SP || s0 + 1 < SV)
      *(h2*)(vT + d * VSTRIDE + s0) = pkrtz(av[0], av[1]);
    if (SV == SP || s0 + 3 < SV)
      *(h2*)(vT + d * VSTRIDE + s0 + 2) = pkrtz(av[2], av[3]);
  }
  if (!TEMPORAL) {
    // zero vT cols [134,160) so padded-K PV chunks multiply P*0 (finite)
    for (int idx = tid; idx < 32 * 13; idx += 256) {
      int d = idx / 13, c = 2 * SLOTS_ + 2 * (idx % 13);
      *(h2*)(vT + d * VSTRIDE + c) = pkrtz(0.f, 0.f);
    }
  }
  __syncthreads();

  // ---- phase 3: MFMA attention, S^T formulation ----
  // wave wv = head h; loop q-tiles mt. Per k-tile:
  //   S^T tile = mfma16x16x32(A=K rows masked to quad h, B=Q rows of mt)
  //   exp2 -> pT (B-frag of 16x16x16) ; O^T += vT-frag * pT ; normalize.
  {
    const int h = wv;
    const h8 z8 = {};
    const _Float16* vrow = vT + (h * 8 + (lm & 7)) * VSTRIDE;
    for (int mt = 0; mt < MT; mt++) {
      h8 bQ = *(const h8*)(qb + (mt * 16 + lm) * 32 + lq * 8);
      const int q = mt * 16 + lm;
      fx4 oaccT = fz;
      float lsum = 0.f;

      auto ktile = [&](int kt, int mode) {
        // mode 0: no mask; 1: keep kidx<67; 2: keep kidx>=67; 3: keep kidx<134
        h8 aK = *(const h8*)(kb + (kt * 16 + lm) * 32 + lq * 8);
        aK = (lq == h) ? aK : z8;  // keep head-h dims only
        fx4 sc = mfma16(aK, bQ, fz);
        float ev[4];
#pragma unroll
        for (int r = 0; r < 4; r++) {
          float x = __builtin_amdgcn_exp2f(sc[r]);
          int kidx = kt * 16 + lq * 4 + r;
          if (mode == 1) x = (kidx < SLOTS_) ? x : 0.f;
          else if (mode == 2) x = (kidx >= SLOTS_) ? x : 0.f;
          else if (mode == 3) x = (kidx < 2 * SLOTS_) ? x : 0.f;
          else if (mode == 4) {
            bool ok = (kidx < 2 * SLOTS_) && ((kidx < SLOTS_) == (q < SLOTS_));
            x = ok ? x : 0.f;
          }
          ev[r] = x;
          lsum += x;
        }
        H4u pT;
        pT.h[0] = pkrtz(ev[0], ev[1]);
        pT.h[1] = pkrtz(ev[2], ev[3]);
        h4 aV = *(const h4*)(vrow + kt * 16 + lq * 4);
        oaccT = mfma16k16(aV, pT.v, oaccT);
      };

      if (TEMPORAL) {
#pragma unroll
        for (int kt = 0; kt < SP / 16; kt++) ktile(kt, 0);
      } else if (mt <= 3) {          // seq0 queries: k-tiles 0..4
#pragma unroll
        for (int kt = 0; kt < 4; kt++) ktile(kt, 0);
        ktile(4, 1);
      } else if (mt == 4) {          // boundary tile: full masked sweep
#pragma unroll
        for (int kt = 0; kt < MT; kt++) ktile(kt, 4);
      } else {                       // seq1 queries: k-tiles 4..8
        ktile(4, 2);
#pragma unroll
        for (int kt = 5; kt < 8; kt++) ktile(kt, 0);
        ktile(8, 3);
      }

      lsum += __shfl_xor(lsum, 16);
      lsum += __shfl_xor(lsum, 32);
      float inv = 1.0f / lsum;
      if (lq < 2 && (SV == SP || q < SV)) {
        H4u ov;
        ov.h[0] = pkrtz(oaccT[0] * inv, oaccT[1] * inv);
        ov.h[1] = pkrtz(oaccT[2] * inv, oaccT[3] * inv);
        *(h4*)(hb + q * 32 + h * 8 + lq * 4) = ov.v;  // h dead -> o
      }
    }
  }
  __syncthreads();

  // ---- phase 4: ao = MFMA(o, Wo) -> aob (fp16) ----
  for (int u = wv; u < MT * 2; u += 4) {
    const int mt = u >> 1, nt = u & 1;
    h8 aO = *(const h8*)(hb + (mt * 16 + lm) * 32 + lq * 8);
    h8 bo = *(const h8*)(W16 + 3072 + (nt * 16 + lm) * 32 + lq * 8);
    fx4 acc = mfma16(aO, bo, fz);
#pragma unroll
    for (int r = 0; r < 4; r++) {
      int s = mt * 16 + lq * 4 + r;
      if (SV == SP || s < SV) aob[s * 32 + nt * 16 + lm] = (_Float16)acc[r];
    }
  }
  __syncthreads();
  // ---- phase 4 epilogue: x += rms(ao); h2 = rms(x) -> hb ----
#pragma unroll
  for (int k = 0; k < SREG; k++) {
    int r = srow + 8 * k;
    if (SV % 8 == 0 || r < SV) {
      float a = (float)aob[r * 32 + e];
      float ss = red32(a * a);
      xr[k] += a * rsqrtf(ss * (1.0f / E_) + 1e-6f) * nw1;
      float hx = xr[k];
      float s2 = red32(hx * hx);
      hb[r * 32 + e] = (_Float16)(hx * rsqrtf(s2 * (1.0f / E_) + 1e-6f) * nw2);
    }
  }
  __syncthreads();

  // ---- phase 5: ffn = silu(MFMA(h2,Wg)) * MFMA(h2,Wvl) -> ffnb ----
  for (int u = wv; u < MT * 4; u += 4) {
    const int mt = u >> 2, nt = u & 3;
    h8 aH2 = *(const h8*)(hb + (mt * 16 + lm) * 32 + lq * 8);
    h8 bg = *(const h8*)(W16 + 4096 + (nt * 16 + lm) * 32 + lq * 8);
    h8 bl = *(const h8*)(W16 + 6144 + (nt * 16 + lm) * 32 + lq * 8);
    fx4 g = mfma16(aH2, bg, fz);
    fx4 vvv = mfma16(aH2, bl, fz);
#pragma unroll
    for (int r = 0; r < 4; r++) {
      int s = mt * 16 + lq * 4 + r;
      if (SV == SP || s < SV) {
        float gg = g[r];
        float sg = gg / (1.0f + __expf(-gg));
        ffnb[s * 64 + nt * 16 + lm] = (_Float16)(sg * vvv[r]);
      }
    }
  }
  __syncthreads();

  // ---- phase 6: out = MFMA(ffn, Wout^T) [K=64 via 2 chained] -> outb ----
  for (int u = wv; u < MT * 2; u += 4) {
    const int mt = u >> 1, nt = u & 1;
    h8 a0 = *(const h8*)(ffnb + (mt * 16 + lm) * 64 + lq * 8);
    h8 a1 = *(const h8*)(ffnb + (mt * 16 + lm) * 64 + 32 + lq * 8);
    h8 b0 = *(const h8*)(W16 + 8192 + (nt * 16 + lm) * 64 + lq * 8);
    h8 b1 = *(const h8*)(W16 + 8192 + (nt * 16 + lm) * 64 + 32 + lq * 8);
    fx4 acc = mfma16(a1, b1, mfma16(a0, b0, fz));
#pragma unroll
    for (int r = 0; r < 4; r++) {
      int s = mt * 16 + lq * 4 + r;
      if (SV == SP || s < SV) outb[s * 32 + nt * 16 + lm] = (_Float16)acc[r];
    }
  }
  __syncthreads();
  // ---- phase 6 epilogue: x += rms(out), store fp16 ----
#pragma unroll
  for (int k = 0; k < SREG; k++) {
    int r = srow + 8 * k;
    if (SV % 8 == 0 || r < SV) {
      float a = (float)outb[r * 32 + e];
      float ss = red32(a * a);
      xr[k] += a * rsqrtf(ss * (1.0f / E_) + 1e-6f) * nw3;
      X[base + r * stride + e] = (_Float16)xr[k];
    }
  }
}

__global__ __launch_bounds__(256, 4) void attn_spatial_kernel(
    _Float16* __restrict__ X, const _Float16* __restrict__ W16,
    const float* __restrict__ norm4, const float* __restrict__ qkn) {
  block_body<2 * SLOTS_, 144, false>(X, W16, norm4, qkn, blockIdx.x);
}

__global__ __launch_bounds__(256, 4) void attn_temporal_kernel(
    _Float16* __restrict__ X, const _Float16* __restrict__ W16,
    const float* __restrict__ norm4, const float* __restrict__ qkn) {
  block_body<T_, 128, true>(X, W16, norm4, qkn, blockIdx.x);
}

// ---------------- final norm + output extraction ----------------
__global__ __launch_bounds__(256) void final_kernel(const _Float16* __restrict__ X,
                                                    const float* __restrict__ fnw,
                                                    float* __restrict__ out) {
  int tok = blockIdx.x * 8 + (threadIdx.x >> 5);
  int e = threadIdx.x & 31;
  if (tok >= B_ * 3) return;
  int b = tok / 3, j = tok % 3;
  const _Float16* xp = X + ((size_t)(b * T_ + (T_ - 1)) * SLOTS_ + OBS_ + j) * E_;
  float v = (float)xp[e];
  float ss = red32(v * v);
  out[j * (B_ * E_) + b * E_ + e] = v * rsqrtf(ss * (1.0f / E_) + 1e-6f) * fnw[e];
}

extern "C" void kernel_launch(void* const* d_in, const int* in_sizes, int n_in,
                              void* d_out, int out_size, void* d_ws, size_t ws_size,
                              hipStream_t stream) {
  (void)in_sizes; (void)n_in; (void)out_size; (void)ws_size;
  const float* obs          = (const float*)d_in[0];
  const float* W_val        = (const float*)d_in[1];
  const float* b_val        = (const float*)d_in[2];
  const float* input_norm_w = (const float*)d_in[3];
  const float* dim_embed    = (const float*)d_in[4];
  const float* cls_tokens   = (const float*)d_in[5];
  const float* final_norm_w = (const float*)d_in[6];
  const float* s_n4   = (const float*)d_in[14];
  const float* s_qkn  = (const float*)d_in[15];
  const float* t_n4   = (const float*)d_in[23];
  const float* t_qkn  = (const float*)d_in[24];

  _Float16* X = (_Float16*)d_ws;  // fp16 residual stream, 8.78 MB
  _Float16* W16 = (_Float16*)((char*)d_ws + X16_BYTES);  // 5*10240 halves
  float* out = (float*)d_out;

  WPtrs wp;
  wp.sWq   = (const float*)d_in[7];
  wp.sWk   = (const float*)d_in[8];
  wp.sWv   = (const float*)d_in[9];
  wp.sWo   = (const float*)d_in[10];
  wp.sWg   = (const float*)d_in[11];
  wp.sWvl  = (const float*)d_in[12];
  wp.sWout = (const float*)d_in[13];
  wp.tWq   = (const float*)d_in[16];
  wp.tWk   = (const float*)d_in[17];
  wp.tWv   = (const float*)d_in[18];
  wp.tWo   = (const float*)d_in[19];
  wp.tWg   = (const float*)d_in[20];
  wp.tWvl  = (const float*)d_in[21];
  wp.tWout = (const float*)d_in[22];

  const int total_tokens = B_ * T_ * SLOTS_;
  const int embed_blocks = (total_tokens + 7) / 8;
  setup_kernel<<<CVT_BLOCKS + embed_blocks, 256, 0, stream>>>(
      wp, W16, obs, W_val, b_val, input_norm_w, dim_embed, cls_tokens, X);

  const int N4 = 4 * E_;   // 128
  const int QN = 2 * HD_;  // 16

#define SPATIAL(i)                                                     \
  attn_spatial_kernel<<<B_ * T_ / 2, 256, 0, stream>>>(                \
      X, W16 + (i)*WBLK, s_n4 + (i)*N4, s_qkn + (i)*QN)
#define TEMPORAL(i)                                                    \
  attn_temporal_kernel<<<B_ * SLOTS_, 256, 0, stream>>>(               \
      X, W16 + (3 + (i)) * WBLK, t_n4 + (i)*N4, t_qkn + (i)*QN)

  SPATIAL(0);
  TEMPORAL(0);
  SPATIAL(1);
  TEMPORAL(1);
  SPATIAL(2);

#undef SPATIAL
#undef TEMPORAL

  final_kernel<<<6, 256, 0, stream>>>(X, final_norm_w, out);
}

// Round 16
// 340.471 us; speedup vs baseline: 1.6650x; 1.1011x over previous
//
#include <hip/hip_runtime.h>

#define B_ 16
#define T_ 128
#define OBS_ 64
#define SLOTS_ 67
#define E_ 32
#define H_ 4
#define HD_ 8
#define FFN_ 64

typedef _Float16 h2 __attribute__((ext_vector_type(2)));
typedef _Float16 h4 __attribute__((ext_vector_type(4)));
typedef _Float16 h8 __attribute__((ext_vector_type(8)));
typedef __fp16 mh4 __attribute__((ext_vector_type(4)));
typedef __fp16 mh8 __attribute__((ext_vector_type(8)));
typedef float fx4 __attribute__((ext_vector_type(4)));
union H4u { h4 v; h2 h[2]; };

// fp16 weight block layout (halves): Wq 0 | Wk 1024 | Wv 2048 | Wo 3072 |
// Wg 4096 | Wvl 6144 | Wout 8192  (10240 halves per transformer block)
#define WBLK 10240
#define X16_BYTES (B_ * T_ * SLOTS_ * E_ * 2)  // 8,781,824 (X stored fp16)

__device__ __forceinline__ float red32(float v) {
  v += __shfl_xor(v, 16); v += __shfl_xor(v, 8); v += __shfl_xor(v, 4);
  v += __shfl_xor(v, 2);  v += __shfl_xor(v, 1);
  return v;
}
__device__ __forceinline__ float red8(float v) {
  v += __shfl_xor(v, 4); v += __shfl_xor(v, 2); v += __shfl_xor(v, 1);
  return v;
}
__device__ __forceinline__ float bfly16(float v) {
  v += __shfl_xor(v, 1); v += __shfl_xor(v, 2);
  v += __shfl_xor(v, 4); v += __shfl_xor(v, 8);
  return v;
}
__device__ __forceinline__ h2 pkrtz(float x, float y) {
  return __builtin_bit_cast(h2, __builtin_amdgcn_cvt_pkrtz(x, y));
}
__device__ __forceinline__ fx4 mfma16(h8 a, h8 b, fx4 c) {
  return __builtin_amdgcn_mfma_f32_16x16x32_f16(
      __builtin_bit_cast(mh8, a), __builtin_bit_cast(mh8, b), c, 0, 0, 0);
}
__device__ __forceinline__ fx4 mfma16k16(h4 a, h4 b, fx4 c) {
  return __builtin_amdgcn_mfma_f32_16x16x16f16(
      __builtin_bit_cast(mh4, a), __builtin_bit_cast(mh4, b), c, 0, 0, 0);
}

// ---------------- setup: weight fp16 conversion + embed, one kernel ----------
struct WPtrs {
  const float *sWq, *sWk, *sWv, *sWo, *sWg, *sWvl, *sWout;
  const float *tWq, *tWk, *tWv, *tWo, *tWg, *tWvl, *tWout;
};

#define CVT_BLOCKS 100

__global__ __launch_bounds__(256) void setup_kernel(
    WPtrs p, _Float16* __restrict__ dst,
    const float* __restrict__ obs, const float* __restrict__ Wval,
    const float* __restrict__ bval, const float* __restrict__ innw,
    const float* __restrict__ dimemb, const float* __restrict__ cls,
    _Float16* __restrict__ X) {
  if (blockIdx.x < CVT_BLOCKS) {
    int i = blockIdx.x * 256 + threadIdx.x;  // pair index
    const int total_pairs = 5 * WBLK / 2;    // 25600
    if (i >= total_pairs) return;
    int blk = i / (WBLK / 2);
    int f = (i % (WBLK / 2)) * 2;
    bool sp = blk < 3;
    int bi = sp ? blk : blk - 3;
    const float* src;
    int o;
    if (f < 1024)      { src = (sp ? p.sWq : p.tWq) + bi * 1024;  o = f; }
    else if (f < 2048) { src = (sp ? p.sWk : p.tWk) + bi * 1024;  o = f - 1024; }
    else if (f < 3072) { src = (sp ? p.sWv : p.tWv) + bi * 1024;  o = f - 2048; }
    else if (f < 4096) { src = (sp ? p.sWo : p.tWo) + bi * 1024;  o = f - 3072; }
    else if (f < 6144) { src = (sp ? p.sWg : p.tWg) + bi * 2048;  o = f - 4096; }
    else if (f < 8192) { src = (sp ? p.sWvl : p.tWvl) + bi * 2048; o = f - 6144; }
    else               { src = (sp ? p.sWout : p.tWout) + bi * 2048; o = f - 8192; }
    ((h2*)dst)[i] = pkrtz(src[o], src[o + 1]);
  } else {
    int tok = (blockIdx.x - CVT_BLOCKS) * 8 + (threadIdx.x >> 5);
    int e = threadIdx.x & 31;
    const int total = B_ * T_ * SLOTS_;
    if (tok >= total) return;
    int slot = tok % SLOTS_;
    int bt = tok / SLOTS_;
    float v;
    if (slot < OBS_) {
      float o = obs[bt * OBS_ + slot];
      v = o * Wval[e] + bval[e] + dimemb[slot * E_ + e];
    } else {
      v = cls[(slot - OBS_) * E_ + e];
    }
    float ss = red32(v * v);
    X[tok * E_ + e] = (_Float16)(v * rsqrtf(ss * (1.0f / E_) + 1e-6f) * innw[e]);
  }
}

// ================= full attention block, all GEMM-shaped math on MFMA ======
// SV = valid rows, SP = padded rows (multiple of 16).
// LDS (halves): [hb SP*32 | qb SP*32 | kb SP*32 | vT].
//   hb: h -> o -> h2 ; ffnb (SV*64) overlays qb+kb.
// Residual xr lives in MFMA C-layout: wave owns mt-tiles (mt ≡ wv mod 4);
// lane holds rows mt*16+lq*4+r, cols lm and lm+16. Row-wide rmsnorm sums
// are 4-shuffle butterflies over lm. Phases 4/6 consume C-frags directly
// (no aob/outb scratch, no fp16 round-trip, 2 fewer barriers).
// Attention: S^T = K_masked · Q^T (16x16x32); exp'd C-frag of S^T is the
// B-operand of 16x16x16 PV (O^T = vT · P^T) -> fully in-register.
// Temporal vT: VSTRIDE=128 with (s-block ^ d&7) swizzle -> LDS exactly
// 32768 B -> 5 blocks/CU. Spatial vT: linear stride 168 (38400 B, 4/CU).
template <int SV, int SP, bool TEMPORAL>
__device__ __forceinline__ void block_body(
    _Float16* __restrict__ X, const _Float16* __restrict__ W16,
    const float* __restrict__ norm4, const float* __restrict__ qkn, int bid) {
  constexpr int MT = SP / 16;
  constexpr int MTW = (MT + 3) / 4;  // mt tiles per wave (ceil)
  constexpr int VSTRIDE = TEMPORAL ? 128 : 168;
  __shared__ __align__(16) _Float16 smem[SP * 96 + 32 * VSTRIDE];
  _Float16* hb = smem;
  _Float16* qb = smem + SP * 32;
  _Float16* kb = smem + SP * 64;
  _Float16* vT = smem + SP * 96;   // [d][s] transposed V
  _Float16* ffnb = qb;             // ffn overlay (SV*64 over qb+kb)

  const int tid = threadIdx.x;
  const int l = tid & 63, wv = tid >> 6;
  const int lm = l & 15, lq = l >> 4, hd = l & 7;

  auto vt_idx = [](int d, int s) {
    if (TEMPORAL) return d * 128 + (((s & ~15) ^ ((d & 7) << 4)) | (s & 15));
    return d * VSTRIDE + s;
  };

  int base, stride;
  if (TEMPORAL) {
    int b = bid / SLOTS_;
    int slot = bid % SLOTS_;
    base = (b * T_ * SLOTS_ + slot) * E_;
    stride = SLOTS_ * E_;
  } else {
    base = bid * 2 * SLOTS_ * E_;  // contiguous 134-row slab
    stride = E_;
  }

  const float nw0a = norm4[lm],      nw0b = norm4[16 + lm];
  const float nw1a = norm4[32 + lm], nw1b = norm4[48 + lm];
  const float nw2a = norm4[64 + lm], nw2b = norm4[80 + lm];
  const float nw3a = norm4[96 + lm], nw3b = norm4[112 + lm];
  const fx4 fz = {0.f, 0.f, 0.f, 0.f};
  const float qw = qkn[hd], kw = qkn[8 + hd];
  const float qscale = 0.35355339059327373f * 1.4426950408889634f;  // 1/sqrt(8)*log2e
  float theta = 0.f;
  if (TEMPORAL) theta = exp2f(-(float)(hd & 3) * 3.3219280948873623f);

  // ---- phase 1: x -> regs (C-layout); h = rmsnorm(x) -> hb ----
  float xr[MTW][4][2];
#pragma unroll
  for (int t = 0; t < MTW; t++) {
    int mt = wv + 4 * t;
    if (mt < MT) {
#pragma unroll
      for (int r = 0; r < 4; r++) {
        int s = mt * 16 + lq * 4 + r;
        bool ok = (SV == SP) || (s < SV);
        int off = base + s * stride;
        xr[t][r][0] = ok ? (float)X[off + lm] : 0.f;
        xr[t][r][1] = ok ? (float)X[off + 16 + lm] : 0.f;
      }
    }
  }
#pragma unroll
  for (int t = 0; t < MTW; t++) {
    int mt = wv + 4 * t;
    if (mt < MT) {
#pragma unroll
      for (int r = 0; r < 4; r++) {
        int s = mt * 16 + lq * 4 + r;
        float p = bfly16(xr[t][r][0] * xr[t][r][0] + xr[t][r][1] * xr[t][r][1]);
        float inv = rsqrtf(p * (1.0f / E_) + 1e-6f);
        if (SV == SP || s < SV) {
          hb[s * 32 + lm] = (_Float16)(xr[t][r][0] * inv * nw0a);
          hb[s * 32 + 16 + lm] = (_Float16)(xr[t][r][1] * inv * nw0b);
        }
      }
    }
  }
  __syncthreads();

  // ---- phase 2: q/k/v = MFMA(h, W) + head rmsnorm + RoPE; v -> vT ----
  for (int u = wv; u < MT * 2; u += 4) {
    const int mt = u >> 1, nt = u & 1;
    h8 aH = *(const h8*)(hb + (mt * 16 + lm) * 32 + lq * 8);
    float rc[4], rs[4];
    if (TEMPORAL) {
#pragma unroll
      for (int r = 0; r < 4; r++) {
        float ang = (float)(mt * 16 + lq * 4 + r) * theta;
        __sincosf(ang, &rs[r], &rc[r]);
      }
    }
    const int d = nt * 16 + lm;
    h8 bq = *(const h8*)(W16 + (nt * 16 + lm) * 32 + lq * 8);
    h8 bk = *(const h8*)(W16 + 1024 + (nt * 16 + lm) * 32 + lq * 8);
    h8 bv = *(const h8*)(W16 + 2048 + (nt * 16 + lm) * 32 + lq * 8);
    fx4 aq = mfma16(aH, bq, fz);
    fx4 ak = mfma16(aH, bk, fz);
    fx4 av = mfma16(aH, bv, fz);
#pragma unroll
    for (int r = 0; r < 4; r++) {
      int s = mt * 16 + lq * 4 + r;
      float q1 = aq[r], k1 = ak[r];
      float qv = q1 * rsqrtf(red8(q1 * q1) * 0.125f + 1e-6f) * qw;
      float kv = k1 * rsqrtf(red8(k1 * k1) * 0.125f + 1e-6f) * kw;
      if (TEMPORAL) {
        float qp = __shfl_xor(qv, 4);
        float kp = __shfl_xor(kv, 4);
        qv = (hd < 4) ? (qv * rc[r] - qp * rs[r]) : (qv * rc[r] + qp * rs[r]);
        kv = (hd < 4) ? (kv * rc[r] - kp * rs[r]) : (kv * rc[r] + kp * rs[r]);
      }
      if (SV == SP || s < SV) {
        qb[s * 32 + d] = (_Float16)(qv * qscale);  // exp2-ready
        kb[s * 32 + d] = (_Float16)kv;
      }
    }
    // v -> vT[d][s], packed pairs (cols s0..s0+3, same 16-block)
    const int s0 = mt * 16 + lq * 4;
    const int va = vt_idx(d, s0);
    if (SV == SP || s0 + 1 < SV) *(h2*)(vT + va) = pkrtz(av[0], av[1]);
    if (SV == SP || s0 + 3 < SV) *(h2*)(vT + va + 2) = pkrtz(av[2], av[3]);
  }
  if (!TEMPORAL) {
    // zero vT cols [134,160) so padded-K PV chunks multiply P*0 (finite)
    for (int idx = tid; idx < 32 * 13; idx += 256) {
      int d = idx / 13, c = 2 * SLOTS_ + 2 * (idx % 13);
      *(h2*)(vT + d * VSTRIDE + c) = pkrtz(0.f, 0.f);
    }
  }
  __syncthreads();

  // ---- phase 3: MFMA attention, S^T formulation ----
  {
    const int h = wv;
    const h8 z8 = {};
    const int dv = h * 8 + (lm & 7);
    for (int mt = 0; mt < MT; mt++) {
      h8 bQ = *(const h8*)(qb + (mt * 16 + lm) * 32 + lq * 8);
      const int q = mt * 16 + lm;
      fx4 oaccT = fz;
      float lsum = 0.f;

      auto ktile = [&](int kt, int mode) {
        // mode 0: no mask; 1: keep kidx<67; 2: keep kidx>=67; 3: keep kidx<134
        h8 aK = *(const h8*)(kb + (kt * 16 + lm) * 32 + lq * 8);
        aK = (lq == h) ? aK : z8;  // keep head-h dims only
        fx4 sc = mfma16(aK, bQ, fz);
        float ev[4];
#pragma unroll
        for (int r = 0; r < 4; r++) {
          float x = __builtin_amdgcn_exp2f(sc[r]);
          int kidx = kt * 16 + lq * 4 + r;
          if (mode == 1) x = (kidx < SLOTS_) ? x : 0.f;
          else if (mode == 2) x = (kidx >= SLOTS_) ? x : 0.f;
          else if (mode == 3) x = (kidx < 2 * SLOTS_) ? x : 0.f;
          else if (mode == 4) {
            bool ok = (kidx < 2 * SLOTS_) && ((kidx < SLOTS_) == (q < SLOTS_));
            x = ok ? x : 0.f;
          }
          ev[r] = x;
          lsum += x;
        }
        H4u pT;
        pT.h[0] = pkrtz(ev[0], ev[1]);
        pT.h[1] = pkrtz(ev[2], ev[3]);
        h4 aV = *(const h4*)(vT + vt_idx(dv, kt * 16 + lq * 4));
        oaccT = mfma16k16(aV, pT.v, oaccT);
      };

      if (TEMPORAL) {
#pragma unroll
        for (int kt = 0; kt < SP / 16; kt++) ktile(kt, 0);
      } else if (mt <= 3) {          // seq0 queries: k-tiles 0..4
#pragma unroll
        for (int kt = 0; kt < 4; kt++) ktile(kt, 0);
        ktile(4, 1);
      } else if (mt == 4) {          // boundary tile: full masked sweep
#pragma unroll
        for (int kt = 0; kt < MT; kt++) ktile(kt, 4);
      } else {                       // seq1 queries: k-tiles 4..8
        ktile(4, 2);
#pragma unroll
        for (int kt = 5; kt < 8; kt++) ktile(kt, 0);
        ktile(8, 3);
      }

      lsum += __shfl_xor(lsum, 16);
      lsum += __shfl_xor(lsum, 32);
      float inv = 1.0f / lsum;
      if (lq < 2 && (SV == SP || q < SV)) {
        H4u ov;
        ov.h[0] = pkrtz(oaccT[0] * inv, oaccT[1] * inv);
        ov.h[1] = pkrtz(oaccT[2] * inv, oaccT[3] * inv);
        *(h4*)(hb + q * 32 + h * 8 + lq * 4) = ov.v;  // h dead -> o
      }
    }
  }
  __syncthreads();

  // ---- phase 4 (fused): ao = MFMA(o, Wo); x += rms(ao); h2 = rms(x) -> hb.
  // All hb reads/writes stay within the owning wave's mt rows: no barrier
  // between compute and h2 store.
#pragma unroll
  for (int t = 0; t < MTW; t++) {
    int mt = wv + 4 * t;
    if (mt < MT) {
      h8 aO = *(const h8*)(hb + (mt * 16 + lm) * 32 + lq * 8);
      h8 b0 = *(const h8*)(W16 + 3072 + lm * 32 + lq * 8);
      h8 b1 = *(const h8*)(W16 + 3072 + (16 + lm) * 32 + lq * 8);
      fx4 a0 = mfma16(aO, b0, fz);
      fx4 a1 = mfma16(aO, b1, fz);
#pragma unroll
      for (int r = 0; r < 4; r++) {
        int s = mt * 16 + lq * 4 + r;
        float p = bfly16(a0[r] * a0[r] + a1[r] * a1[r]);
        float inv = rsqrtf(p * (1.0f / E_) + 1e-6f);
        xr[t][r][0] += a0[r] * inv * nw1a;
        xr[t][r][1] += a1[r] * inv * nw1b;
        float q2 = bfly16(xr[t][r][0] * xr[t][r][0] + xr[t][r][1] * xr[t][r][1]);
        float inv2 = rsqrtf(q2 * (1.0f / E_) + 1e-6f);
        if (SV == SP || s < SV) {
          hb[s * 32 + lm] = (_Float16)(xr[t][r][0] * inv2 * nw2a);
          hb[s * 32 + 16 + lm] = (_Float16)(xr[t][r][1] * inv2 * nw2b);
        }
      }
    }
  }
  __syncthreads();

  // ---- phase 5: ffn = silu(MFMA(h2,Wg)) * MFMA(h2,Wvl) -> ffnb ----
  for (int u = wv; u < MT * 4; u += 4) {
    const int mt = u >> 2, nt = u & 3;
    h8 aH2 = *(const h8*)(hb + (mt * 16 + lm) * 32 + lq * 8);
    h8 bg = *(const h8*)(W16 + 4096 + (nt * 16 + lm) * 32 + lq * 8);
    h8 bl = *(const h8*)(W16 + 6144 + (nt * 16 + lm) * 32 + lq * 8);
    fx4 g = mfma16(aH2, bg, fz);
    fx4 vvv = mfma16(aH2, bl, fz);
#pragma unroll
    for (int r = 0; r < 4; r++) {
      int s = mt * 16 + lq * 4 + r;
      if (SV == SP || s < SV) {
        float gg = g[r];
        float sg = gg / (1.0f + __expf(-gg));
        ffnb[s * 64 + nt * 16 + lm] = (_Float16)(sg * vvv[r]);
      }
    }
  }
  __syncthreads();

  // ---- phase 6 (fused): out = MFMA(ffn, Wout^T); x += rms(out); store X ----
#pragma unroll
  for (int t = 0; t < MTW; t++) {
    int mt = wv + 4 * t;
    if (mt < MT) {
      const _Float16* fr = ffnb + (mt * 16 + lm) * 64;
      h8 a0 = *(const h8*)(fr + lq * 8);
      h8 a1 = *(const h8*)(fr + 32 + lq * 8);
      h8 b00 = *(const h8*)(W16 + 8192 + lm * 64 + lq * 8);
      h8 b01 = *(const h8*)(W16 + 8192 + lm * 64 + 32 + lq * 8);
      h8 b10 = *(const h8*)(W16 + 8192 + (16 + lm) * 64 + lq * 8);
      h8 b11 = *(const h8*)(W16 + 8192 + (16 + lm) * 64 + 32 + lq * 8);
      fx4 o0 = mfma16(a1, b01, mfma16(a0, b00, fz));
      fx4 o1 = mfma16(a1, b11, mfma16(a0, b10, fz));
#pragma unroll
      for (int r = 0; r < 4; r++) {
        int s = mt * 16 + lq * 4 + r;
        float p = bfly16(o0[r] * o0[r] + o1[r] * o1[r]);
        float inv = rsqrtf(p * (1.0f / E_) + 1e-6f);
        xr[t][r][0] += o0[r] * inv * nw3a;
        xr[t][r][1] += o1[r] * inv * nw3b;
        if (SV == SP || s < SV) {
          int off = base + s * stride;
          X[off + lm] = (_Float16)xr[t][r][0];
          X[off + 16 + lm] = (_Float16)xr[t][r][1];
        }
      }
    }
  }
}

__global__ __launch_bounds__(256, 4) void attn_spatial_kernel(
    _Float16* __restrict__ X, const _Float16* __restrict__ W16,
    const float* __restrict__ norm4, const float* __restrict__ qkn) {
  block_body<2 * SLOTS_, 144, false>(X, W16, norm4, qkn, blockIdx.x);
}

__global__ __launch_bounds__(256, 5) void attn_temporal_kernel(
    _Float16* __restrict__ X, const _Float16* __restrict__ W16,
    const float* __restrict__ norm4, const float* __restrict__ qkn) {
  block_body<T_, 128, true>(X, W16, norm4, qkn, blockIdx.x);
}

// ---------------- final norm + output extraction ----------------
__global__ __launch_bounds__(256) void final_kernel(const _Float16* __restrict__ X,
                                                    const float* __restrict__ fnw,
                                                    float* __restrict__ out) {
  int tok = blockIdx.x * 8 + (threadIdx.x >> 5);
  int e = threadIdx.x & 31;
  if (tok >= B_ * 3) return;
  int b = tok / 3, j = tok % 3;
  const _Float16* xp = X + ((size_t)(b * T_ + (T_ - 1)) * SLOTS_ + OBS_ + j) * E_;
  float v = (float)xp[e];
  float ss = red32(v * v);
  out[j * (B_ * E_) + b * E_ + e] = v * rsqrtf(ss * (1.0f / E_) + 1e-6f) * fnw[e];
}

extern "C" void kernel_launch(void* const* d_in, const int* in_sizes, int n_in,
                              void* d_out, int out_size, void* d_ws, size_t ws_size,
                              hipStream_t stream) {
  (void)in_sizes; (void)n_in; (void)out_size; (void)ws_size;
  const float* obs          = (const float*)d_in[0];
  const float* W_val        = (const float*)d_in[1];
  const float* b_val        = (const float*)d_in[2];
  const float* input_norm_w = (const float*)d_in[3];
  const float* dim_embed    = (const float*)d_in[4];
  const float* cls_tokens   = (const float*)d_in[5];
  const float* final_norm_w = (const float*)d_in[6];
  const float* s_n4   = (const float*)d_in[14];
  const float* s_qkn  = (const float*)d_in[15];
  const float* t_n4   = (const float*)d_in[23];
  const float* t_qkn  = (const float*)d_in[24];

  _Float16* X = (_Float16*)d_ws;  // fp16 residual stream, 8.78 MB
  _Float16* W16 = (_Float16*)((char*)d_ws + X16_BYTES);  // 5*10240 halves
  float* out = (float*)d_out;

  WPtrs wp;
  wp.sWq   = (const float*)d_in[7];
  wp.sWk   = (const float*)d_in[8];
  wp.sWv   = (const float*)d_in[9];
  wp.sWo   = (const float*)d_in[10];
  wp.sWg   = (const float*)d_in[11];
  wp.sWvl  = (const float*)d_in[12];
  wp.sWout = (const float*)d_in[13];
  wp.tWq   = (const float*)d_in[16];
  wp.tWk   = (const float*)d_in[17];
  wp.tWv   = (const float*)d_in[18];
  wp.tWo   = (const float*)d_in[19];
  wp.tWg   = (const float*)d_in[20];
  wp.tWvl  = (const float*)d_in[21];
  wp.tWout = (const float*)d_in[22];

  const int total_tokens = B_ * T_ * SLOTS_;
  const int embed_blocks = (total_tokens + 7) / 8;
  setup_kernel<<<CVT_BLOCKS + embed_blocks, 256, 0, stream>>>(
      wp, W16, obs, W_val, b_val, input_norm_w, dim_embed, cls_tokens, X);

  const int N4 = 4 * E_;   // 128
  const int QN = 2 * HD_;  // 16

#define SPATIAL(i)                                                     \
  attn_spatial_kernel<<<B_ * T_ / 2, 256, 0, stream>>>(                \
      X, W16 + (i)*WBLK, s_n4 + (i)*N4, s_qkn + (i)*QN)
#define TEMPORAL(i)                                                    \
  attn_temporal_kernel<<<B_ * SLOTS_, 256, 0, stream>>>(               \
      X, W16 + (3 + (i)) * WBLK, t_n4 + (i)*N4, t_qkn + (i)*QN)

  SPATIAL(0);
  TEMPORAL(0);
  SPATIAL(1);
  TEMPORAL(1);
  SPATIAL(2);

#undef SPATIAL
#undef TEMPORAL

  final_kernel<<<6, 256, 0, stream>>>(X, final_norm_w, out);
}